// Round 1
// baseline (373.779 us; speedup 1.0000x reference)
//
#include <hip/hip_runtime.h>

// OccupancyConnectivity: sum over 3 forward directions of |occ[i+1]-occ[i]|
// Grid is 385^3 fp32, contiguous, z innermost (stride 1), y stride 385,
// x stride 385*385 = 148225.

constexpr int          G     = 385;
constexpr int          PLANE = G * G;                    // 148225
constexpr long long    NTOT  = (long long)G * PLANE;     // 57,066,625 (odd)
constexpr int          N4    = (int)((NTOT + 3) / 4);    // 14,266,657 float4 work items

#define TPB    256
#define BLOCKS 2048   // 8 blocks/CU on 256 CUs; 2048 partials into d_ws

__global__ __launch_bounds__(TPB) void occ_conn_partial(
    const float* __restrict__ a, float* __restrict__ ws)
{
    float s = 0.f;
    const int stride = BLOCKS * TPB;
    for (int i = blockIdx.x * TPB + threadIdx.x; i < N4; i += stride) {
        const long long p0 = (long long)i * 4;
        if (p0 + 4 < NTOT) {
            // fast path: aligned float4 + the next scalar (for element 3's z-diff)
            const float4 v4 = *(const float4*)(a + p0);
            const float v[4] = {v4.x, v4.y, v4.z, v4.w};
            const float vnext = a[p0 + 4];
            #pragma unroll
            for (int e = 0; e < 4; ++e) {
                const unsigned p = (unsigned)p0 + (unsigned)e;
                const unsigned x = p / (unsigned)PLANE;          // magic-mul div
                const unsigned r = p - x * (unsigned)PLANE;
                const unsigned y = r / (unsigned)G;
                const unsigned z = r - y * (unsigned)G;
                const float v0 = v[e];
                if (z < (unsigned)(G - 1)) {
                    const float zn = (e < 3) ? v[e + 1] : vnext;
                    s += fabsf(zn - v0);
                }
                if (y < (unsigned)(G - 1)) s += fabsf(a[p + G] - v0);
                if (x < (unsigned)(G - 1)) s += fabsf(a[p + PLANE] - v0);
            }
        } else {
            // tail (at most 4 scalar elements at the very end of the array)
            #pragma unroll
            for (int e = 0; e < 4; ++e) {
                const long long pl = p0 + e;
                if (pl >= NTOT) break;
                const unsigned p = (unsigned)pl;
                const unsigned x = p / (unsigned)PLANE;
                const unsigned r = p - x * (unsigned)PLANE;
                const unsigned y = r / (unsigned)G;
                const unsigned z = r - y * (unsigned)G;
                const float v0 = a[p];
                if (z < (unsigned)(G - 1)) s += fabsf(a[p + 1]     - v0);
                if (y < (unsigned)(G - 1)) s += fabsf(a[p + G]     - v0);
                if (x < (unsigned)(G - 1)) s += fabsf(a[p + PLANE] - v0);
            }
        }
    }

    // wave (64-lane) shuffle reduction
    #pragma unroll
    for (int off = 32; off > 0; off >>= 1) s += __shfl_down(s, off, 64);

    __shared__ float ls[TPB / 64];
    const int lane = threadIdx.x & 63;
    const int wid  = threadIdx.x >> 6;
    if (lane == 0) ls[wid] = s;
    __syncthreads();
    if (threadIdx.x == 0) {
        float t = 0.f;
        #pragma unroll
        for (int w = 0; w < TPB / 64; ++w) t += ls[w];
        ws[blockIdx.x] = t;
    }
}

__global__ __launch_bounds__(256) void occ_conn_final(
    const float* __restrict__ ws, float* __restrict__ out)
{
    float s = 0.f;
    for (int i = threadIdx.x; i < BLOCKS; i += 256) s += ws[i];
    #pragma unroll
    for (int off = 32; off > 0; off >>= 1) s += __shfl_down(s, off, 64);
    __shared__ float ls[4];
    const int lane = threadIdx.x & 63;
    const int wid  = threadIdx.x >> 6;
    if (lane == 0) ls[wid] = s;
    __syncthreads();
    if (threadIdx.x == 0) out[0] = ls[0] + ls[1] + ls[2] + ls[3];
}

extern "C" void kernel_launch(void* const* d_in, const int* in_sizes, int n_in,
                              void* d_out, int out_size, void* d_ws, size_t ws_size,
                              hipStream_t stream)
{
    const float* a   = (const float*)d_in[0];
    float*       out = (float*)d_out;
    float*       ws  = (float*)d_ws;   // BLOCKS floats of scratch (poisoned each call; fully overwritten)

    occ_conn_partial<<<BLOCKS, TPB, 0, stream>>>(a, ws);
    occ_conn_final<<<1, 256, 0, stream>>>(ws, out);
}

// Round 2
// 325.444 us; speedup vs baseline: 1.1485x; 1.1485x over previous
//
#include <hip/hip_runtime.h>

// OccupancyConnectivity on a 385^3 fp32 grid, z innermost.
// total = sum over 3 forward axes of |a[p+off]-a[p]| with validity masks.
//
// Strategy: branchless main sweep over the first 384 x-planes adding ALL
// three diffs unconditionally (no div/mod, wide loads), then a small fixup
// that (a) subtracts the bogus z-pairs at row boundaries, (b) subtracts the
// bogus y-pairs at plane boundaries, (c) adds the last x-plane's z/y diffs.
// Blocks are slab-swizzled (blockIdx%8 -> XCD) so the +G / +PLANE re-reads
// hit the XCD-local L2.

constexpr int      G      = 385;
constexpr int      PLANE  = G * G;                 // 148225
constexpr unsigned NTOT   = 57066625u;             // 385^3
constexpr unsigned NA     = 384u * PLANE;          // 56918400, first 384 planes
constexpr unsigned SLAB   = NA / 8;                // 7114800 elems per XCD slab
constexpr unsigned SLAB8  = SLAB / 8;              // 889350 8-elem items
constexpr unsigned NROWB  = 147840u;               // z-boundary rows in region A
constexpr unsigned NYB    = 147840u;               // y-boundary elems (x<384)

#define TPB        256
#define FIX_BLOCKS 64
#define SUB_BLOCKS 248                              // main blocks per slab
#define MAIN_BLOCKS (SUB_BLOCKS * 8)                // 1984
#define ALL_BLOCKS  (FIX_BLOCKS + MAIN_BLOCKS)      // 2048

typedef float f4v __attribute__((ext_vector_type(4)));
typedef f4v f4u __attribute__((aligned(4)));

static __device__ __forceinline__ f4v ld4a(const float* p) { return *(const f4v*)p; }
static __device__ __forceinline__ f4v ld4u(const float* p) { return *(const f4u*)p; }

__global__ __launch_bounds__(TPB) void occ_conn_main(
    const float* __restrict__ a, float* __restrict__ ws)
{
    float s = 0.f;
    const int bid = blockIdx.x;

    if (bid < FIX_BLOCKS) {
        // ---- fixup role (runs first so it overlaps the streaming blocks) ----
        const unsigned ft = (unsigned)bid * TPB + threadIdx.x;
        const unsigned NF = FIX_BLOCKS * TPB;

        // C1: subtract bogus z-pairs at row boundaries (z==384), rows r in [0,147840)
        for (unsigned r = ft; r < NROWB; r += NF) {
            const unsigned p = r * (unsigned)G + 384u;
            s -= fabsf(a[p + 1] - a[p]);
        }
        // C2: subtract bogus y-pairs at plane boundaries (y==384, x<384)
        for (unsigned j = ft; j < NYB; j += NF) {
            const unsigned x = j / (unsigned)G;
            const unsigned z = j - x * (unsigned)G;
            const unsigned q = x * (unsigned)PLANE + 384u * (unsigned)G + z;
            s -= fabsf(a[q + G] - a[q]);
        }
        // B: last x-plane (x==384): valid z- and y-diffs
        for (unsigned j = ft; j < (unsigned)PLANE; j += NF) {
            const unsigned y = j / (unsigned)G;
            const unsigned z = j - y * (unsigned)G;
            const unsigned p = NA + j;
            if (z < 384u) s += fabsf(a[p + 1] - a[p]);
            if (y < 384u) s += fabsf(a[p + G] - a[p]);
        }
    } else {
        // ---- main streaming role: branchless 3-diff sweep over region A ----
        const int mid  = bid - FIX_BLOCKS;
        const unsigned slab = (unsigned)(mid & 7);        // -> XCD via %8 round-robin
        const unsigned sub  = (unsigned)(mid >> 3);       // 0..SUB_BLOCKS-1
        const unsigned base = slab * SLAB;

        for (unsigned it = sub * TPB + threadIdx.x; it < SLAB8; it += SUB_BLOCKS * TPB) {
            const unsigned p = base + it * 8u;
            const f4v f0 = ld4a(a + p);
            const f4v f1 = ld4a(a + p + 4);
            const f4v g0 = ld4u(a + p + G);
            const f4v g1 = ld4u(a + p + G + 4);
            const f4v h0 = ld4u(a + p + PLANE);
            const f4v h1 = ld4u(a + p + PLANE + 4);
            const float fn = a[p + 8];

            // z-diffs (8 pairs, from registers)
            s += fabsf(f0.y - f0.x) + fabsf(f0.z - f0.y) + fabsf(f0.w - f0.z)
               + fabsf(f1.x - f0.w) + fabsf(f1.y - f1.x) + fabsf(f1.z - f1.y)
               + fabsf(f1.w - f1.z) + fabsf(fn   - f1.w);
            // y-diffs
            s += fabsf(g0.x - f0.x) + fabsf(g0.y - f0.y) + fabsf(g0.z - f0.z)
               + fabsf(g0.w - f0.w) + fabsf(g1.x - f1.x) + fabsf(g1.y - f1.y)
               + fabsf(g1.z - f1.z) + fabsf(g1.w - f1.w);
            // x-diffs
            s += fabsf(h0.x - f0.x) + fabsf(h0.y - f0.y) + fabsf(h0.z - f0.z)
               + fabsf(h0.w - f0.w) + fabsf(h1.x - f1.x) + fabsf(h1.y - f1.y)
               + fabsf(h1.z - f1.z) + fabsf(h1.w - f1.w);
        }
    }

    // wave (64-lane) shuffle reduction
    #pragma unroll
    for (int off = 32; off > 0; off >>= 1) s += __shfl_down(s, off, 64);

    __shared__ float ls[TPB / 64];
    const int lane = threadIdx.x & 63;
    const int wid  = threadIdx.x >> 6;
    if (lane == 0) ls[wid] = s;
    __syncthreads();
    if (threadIdx.x == 0) {
        float t = 0.f;
        #pragma unroll
        for (int w = 0; w < TPB / 64; ++w) t += ls[w];
        ws[blockIdx.x] = t;
    }
}

__global__ __launch_bounds__(256) void occ_conn_final(
    const float* __restrict__ ws, float* __restrict__ out)
{
    float s = 0.f;
    for (int i = threadIdx.x; i < ALL_BLOCKS; i += 256) s += ws[i];
    #pragma unroll
    for (int off = 32; off > 0; off >>= 1) s += __shfl_down(s, off, 64);
    __shared__ float ls[4];
    const int lane = threadIdx.x & 63;
    const int wid  = threadIdx.x >> 6;
    if (lane == 0) ls[wid] = s;
    __syncthreads();
    if (threadIdx.x == 0) out[0] = ls[0] + ls[1] + ls[2] + ls[3];
}

extern "C" void kernel_launch(void* const* d_in, const int* in_sizes, int n_in,
                              void* d_out, int out_size, void* d_ws, size_t ws_size,
                              hipStream_t stream)
{
    const float* a   = (const float*)d_in[0];
    float*       out = (float*)d_out;
    float*       ws  = (float*)d_ws;   // ALL_BLOCKS floats; fully overwritten each call

    occ_conn_main<<<ALL_BLOCKS, TPB, 0, stream>>>(a, ws);
    occ_conn_final<<<1, 256, 0, stream>>>(ws, out);
}